// Round 4
// baseline (430.396 us; speedup 1.0000x reference)
//
#include <hip/hip_runtime.h>
#include <hip/hip_bf16.h>

typedef __attribute__((ext_vector_type(8))) short short8;
typedef __attribute__((ext_vector_type(4))) float f32x4;

#define N_NODES 20000
#define N_EDGES 320000
#define NFEAT 512
#define NHID 1024

__device__ __forceinline__ float bf2f(unsigned short u) {
    union { unsigned int i; float f; } c; c.i = ((unsigned int)u) << 16; return c.f;
}
__device__ __forceinline__ unsigned short f2bf(float f) {
    union { float f; unsigned int i; } c; c.f = f;
    unsigned int x = c.i;
    return (unsigned short)((x + 0x7fffu + ((x >> 16) & 1u)) >> 16);
}

__device__ __forceinline__ void gload_lds16(const void* g, void* l) {
    __builtin_amdgcn_global_load_lds(
        (const __attribute__((address_space(1))) void*)g,
        (__attribute__((address_space(3))) void*)l, 16, 0, 0);
}

// ---------------- CSR build ----------------

__global__ void hist_kernel(const int* __restrict__ dst, int* __restrict__ deg, int E) {
    int e = blockIdx.x * 256 + threadIdx.x;
    if (e < E) atomicAdd(&deg[dst[e]], 1);
}

__global__ __launch_bounds__(1024) void scan_kernel(const int* __restrict__ deg,
                                                    int* __restrict__ row_ptr,
                                                    int* __restrict__ cursor, int n) {
    __shared__ int sdata[1024];
    const int t = threadIdx.x;
    constexpr int CH = 20;  // 1024*20 = 20480 >= 20000
    int base = t * CH;
    int local[CH];
    int sum = 0;
#pragma unroll
    for (int i = 0; i < CH; ++i) {
        int idx = base + i;
        int v = (idx < n) ? deg[idx] : 0;
        local[i] = sum;
        sum += v;
    }
    sdata[t] = sum;
    __syncthreads();
    for (int off = 1; off < 1024; off <<= 1) {
        int v = (t >= off) ? sdata[t - off] : 0;
        __syncthreads();
        sdata[t] += v;
        __syncthreads();
    }
    int prev = (t == 0) ? 0 : sdata[t - 1];
#pragma unroll
    for (int i = 0; i < CH; ++i) {
        int idx = base + i;
        if (idx < n) {
            int p = prev + local[i];
            row_ptr[idx] = p;
            cursor[idx]  = p;
        }
    }
    if (t == 1023) row_ptr[n] = sdata[1023];
}

__global__ void fill_kernel(const int* __restrict__ src, const int* __restrict__ dst,
                            const float* __restrict__ vals, int* __restrict__ cursor,
                            int* __restrict__ csr_src, float* __restrict__ csr_val, int E) {
    int e = blockIdx.x * 256 + threadIdx.x;
    if (e < E) {
        int d = dst[e];
        int pos = atomicAdd(&cursor[d], 1);
        csr_src[pos] = src[e];
        csr_val[pos] = vals[e];
    }
}

// ------------- W transpose + bf16 convert:  Wt[n][k] = W[k][n] -------------

__global__ void transpose_cvt(const float* __restrict__ W, unsigned short* __restrict__ Wt,
                              int K, int N) {
    __shared__ float tile[32][33];
    int ntx = N >> 5;
    int k0 = (blockIdx.x / ntx) << 5;
    int n0 = (blockIdx.x % ntx) << 5;
    int tx = threadIdx.x & 31, ty = threadIdx.x >> 5;  // ty 0..7
#pragma unroll
    for (int i = 0; i < 32; i += 8)
        tile[ty + i][tx] = W[(size_t)(k0 + ty + i) * N + n0 + tx];
    __syncthreads();
#pragma unroll
    for (int i = 0; i < 32; i += 8)
        Wt[(size_t)(n0 + ty + i) * K + k0 + tx] = f2bf(tile[tx][ty + i]);
}

// ------------- f32 -> bf16 convert (x) -------------

__global__ void cvt_bf16_kernel(const float* __restrict__ x, unsigned short* __restrict__ xb,
                                int n8) {
    int i = blockIdx.x * 256 + threadIdx.x;
    if (i < n8) {
        f32x4 v0 = ((const f32x4*)x)[i * 2];
        f32x4 v1 = ((const f32x4*)x)[i * 2 + 1];
        short8 o;
#pragma unroll
        for (int j = 0; j < 4; ++j) {
            o[j]     = (short)f2bf(v0[j]);
            o[4 + j] = (short)f2bf(v1[j]);
        }
        ((short8*)xb)[i] = o;
    }
}

// ------------- aggregation 1:  agg[d] = sum_e val_e * xbf[src_e]  (bf16 in, bf16 out) -------------

__global__ __launch_bounds__(64) void agg1_kernel(const unsigned short* __restrict__ xbf,
                                                  const int* __restrict__ csr_src,
                                                  const float* __restrict__ csr_val,
                                                  const int* __restrict__ row_ptr,
                                                  unsigned short* __restrict__ agg) {
    int d = blockIdx.x;
    int l = threadIdx.x;  // 0..63, 8 bf16 each -> 512
    int e0 = row_ptr[d], e1 = row_ptr[d + 1];
    f32x4 a0 = {0.f, 0.f, 0.f, 0.f}, a1 = {0.f, 0.f, 0.f, 0.f};
    int e = e0;
    for (; e + 1 < e1; e += 2) {
        int s0 = csr_src[e], s1 = csr_src[e + 1];
        float v0 = csr_val[e], v1 = csr_val[e + 1];
        short8 w0 = *(const short8*)&xbf[(size_t)s0 * NFEAT + l * 8];
        short8 w1 = *(const short8*)&xbf[(size_t)s1 * NFEAT + l * 8];
#pragma unroll
        for (int j = 0; j < 4; ++j) {
            a0[j] += v0 * bf2f((unsigned short)w0[j]);
            a1[j] += v0 * bf2f((unsigned short)w0[4 + j]);
            a0[j] += v1 * bf2f((unsigned short)w1[j]);
            a1[j] += v1 * bf2f((unsigned short)w1[4 + j]);
        }
    }
    if (e < e1) {
        int s0 = csr_src[e];
        float v0 = csr_val[e];
        short8 w0 = *(const short8*)&xbf[(size_t)s0 * NFEAT + l * 8];
#pragma unroll
        for (int j = 0; j < 4; ++j) {
            a0[j] += v0 * bf2f((unsigned short)w0[j]);
            a1[j] += v0 * bf2f((unsigned short)w0[4 + j]);
        }
    }
    short8 o;
#pragma unroll
    for (int j = 0; j < 4; ++j) {
        o[j]     = (short)f2bf(a0[j]);
        o[4 + j] = (short)f2bf(a1[j]);
    }
    *(short8*)&agg[(size_t)d * NFEAT + l * 8] = o;
}

// ------------- aggregation 2:  out[d] = b2 + sum_e val_e * s2[src_e]  (bf16 in, f32 out) -------------

__global__ __launch_bounds__(64) void agg2_kernel(const unsigned short* __restrict__ s2,
                                                  const int* __restrict__ csr_src,
                                                  const float* __restrict__ csr_val,
                                                  const int* __restrict__ row_ptr,
                                                  const float* __restrict__ b2,
                                                  float* __restrict__ out) {
    int d = blockIdx.x;
    int l = threadIdx.x;  // 0..63, 8 f32 each -> 512
    int e0 = row_ptr[d], e1 = row_ptr[d + 1];
    f32x4 a0 = ((const f32x4*)b2)[l * 2];
    f32x4 a1 = ((const f32x4*)b2)[l * 2 + 1];
    int e = e0;
    for (; e + 1 < e1; e += 2) {
        int s0 = csr_src[e], s1 = csr_src[e + 1];
        float v0 = csr_val[e], v1 = csr_val[e + 1];
        short8 w0 = *(const short8*)&s2[(size_t)s0 * NFEAT + l * 8];
        short8 w1 = *(const short8*)&s2[(size_t)s1 * NFEAT + l * 8];
#pragma unroll
        for (int j = 0; j < 4; ++j) {
            a0[j] += v0 * bf2f((unsigned short)w0[j]);
            a1[j] += v0 * bf2f((unsigned short)w0[4 + j]);
            a0[j] += v1 * bf2f((unsigned short)w1[j]);
            a1[j] += v1 * bf2f((unsigned short)w1[4 + j]);
        }
    }
    if (e < e1) {
        int s0 = csr_src[e];
        float v0 = csr_val[e];
        short8 w0 = *(const short8*)&s2[(size_t)s0 * NFEAT + l * 8];
#pragma unroll
        for (int j = 0; j < 4; ++j) {
            a0[j] += v0 * bf2f((unsigned short)w0[j]);
            a1[j] += v0 * bf2f((unsigned short)w0[4 + j]);
        }
    }
    *(f32x4*)&out[(size_t)d * NFEAT + l * 8]     = a0;
    *(f32x4*)&out[(size_t)d * NFEAT + l * 8 + 4] = a1;
}

// ------------- register-A GEMM:  C[M,N] = A[M,K] * Bt[N,K]^T -------------
// A (full K) lives in registers: each wave owns M_REP*16 rows.
// B column-panel (NB cols, full K) double-buffered in XOR-swizzled LDS; one
// barrier per N-chunk; panel staging for chunk c+1 issued before chunk c's
// compute so __syncthreads' vmcnt-drain lands after ~2500 cyc of MFMA.
// EPI==1: C = bf16(dropout(relu(acc + bias)))   EPI==0: C = bf16(acc)

template <int EPI, int WAVES, int M_REP, int N_REP, int KTILES>
__global__ __launch_bounds__(WAVES * 64) void gemm_rs(
    const unsigned short* __restrict__ A,
    const unsigned short* __restrict__ Bt,
    unsigned short* __restrict__ C,
    int M, int N,
    const float* __restrict__ bias,
    const float* __restrict__ u_drop) {
    constexpr int K = KTILES * 32;
    constexpr int NB = N_REP * 16;
    constexpr int BM = WAVES * M_REP * 16;
    constexpr int HPR = K / 512;              // 1KB staging units per panel row
    constexpr int GPW = (NB * HPR) / WAVES;   // gloads per wave per panel
    __shared__ __align__(16) unsigned short lB[2][NB * K];  // 2 x 64 KB

    const int tid = threadIdx.x;
    const int wid = tid >> 6;
    const int lane = tid & 63;
    const int rl = lane & 15;
    const int kq = lane >> 4;                 // 0..3
    const int row0 = blockIdx.x * BM;
    const int wrow = row0 + wid * (M_REP * 16);

    // ---- A into registers (full K), issued before first panel stage ----
    short8 arA[M_REP][KTILES];
#pragma unroll
    for (int mr = 0; mr < M_REP; ++mr) {
        int r = wrow + mr * 16 + rl;
        if (r >= M) r = M - 1;
#pragma unroll
        for (int kt = 0; kt < KTILES; ++kt)
            arA[mr][kt] = *(const short8*)&A[(size_t)r * K + kt * 32 + kq * 8];
    }

    auto stage = [&](int bufi, int c) {
        const int pc0 = c * NB;
#pragma unroll
        for (int i = 0; i < GPW; ++i) {
            int g = wid * GPW + i;
            int row = g / HPR;                // panel row 0..NB-1
            int h = g - row * HPR;            // 1KB half index
            size_t goff = (size_t)(pc0 + row) * K + (size_t)(h * 64 + (lane ^ (row & 7))) * 8;
            gload_lds16(Bt + goff, &lB[bufi][row * K + h * 512]);
        }
    };

    const int NCH = N / NB;
    stage(0, 0);
    __syncthreads();
    int buf = 0;

    for (int c = 0; c < NCH; ++c) {
        if (c + 1 < NCH) stage(buf ^ 1, c + 1);

        f32x4 acc[M_REP][N_REP] = {};
#pragma unroll
        for (int kt = 0; kt < KTILES; ++kt) {
            short8 bfr[N_REP];
#pragma unroll
            for (int nn = 0; nn < N_REP; ++nn) {
                int rb = nn * 16 + rl;
                int sw = (kt * 4 + kq) ^ (rb & 7);
                bfr[nn] = *(const short8*)&lB[buf][rb * K + sw * 8];
            }
#pragma unroll
            for (int mr = 0; mr < M_REP; ++mr)
#pragma unroll
                for (int nn = 0; nn < N_REP; ++nn)
                    acc[mr][nn] = __builtin_amdgcn_mfma_f32_16x16x32_bf16(
                        arA[mr][kt], bfr[nn], acc[mr][nn], 0, 0, 0);
        }

        // epilogue: C/D layout col = rl, row = kq*4 + j
#pragma unroll
        for (int mr = 0; mr < M_REP; ++mr) {
#pragma unroll
            for (int nn = 0; nn < N_REP; ++nn) {
                int gc = c * NB + nn * 16 + rl;
#pragma unroll
                for (int j = 0; j < 4; ++j) {
                    int gr = wrow + mr * 16 + kq * 4 + j;
                    if (gr < M) {
                        float v = acc[mr][nn][j];
                        if (EPI == 1) {
                            v += bias[gc];
                            v = v > 0.f ? v : 0.f;
                            float u = u_drop[(size_t)gr * N + gc];
                            v = (u > 0.5f) ? v * 2.0f : 0.0f;
                        }
                        C[(size_t)gr * N + gc] = f2bf(v);
                    }
                }
            }
        }
        __syncthreads();
        buf ^= 1;
    }
}

// ---------------- launch ----------------

extern "C" void kernel_launch(void* const* d_in, const int* in_sizes, int n_in,
                              void* d_out, int out_size, void* d_ws, size_t ws_size,
                              hipStream_t stream) {
    const float* x        = (const float*)d_in[0];
    const float* W1       = (const float*)d_in[1];
    const float* b1       = (const float*)d_in[2];
    const float* W2       = (const float*)d_in[3];
    const float* b2       = (const float*)d_in[4];
    const float* adj_vals = (const float*)d_in[5];
    const float* u_drop   = (const float*)d_in[6];
    const int*   src      = (const int*)d_in[7];
    const int*   dst      = (const int*)d_in[8];
    float* out = (float*)d_out;

    char* p = (char*)d_ws;
    auto take = [&](size_t bytes) {
        char* q = p;
        p += (bytes + 255) & ~(size_t)255;
        return q;
    };
    int* deg        = (int*)take((size_t)N_NODES * 4);
    int* row_ptr    = (int*)take((size_t)(N_NODES + 1) * 4);
    int* cursor     = (int*)take((size_t)N_NODES * 4);
    int* csr_src    = (int*)take((size_t)N_EDGES * 4);
    float* csr_val  = (float*)take((size_t)N_EDGES * 4);
    unsigned short* w1t   = (unsigned short*)take((size_t)NFEAT * NHID * 2);
    unsigned short* w2t   = (unsigned short*)take((size_t)NFEAT * NHID * 2);
    unsigned short* xbf   = (unsigned short*)take((size_t)N_NODES * NFEAT * 2);
    unsigned short* agg1b = (unsigned short*)take((size_t)N_NODES * NFEAT * 2);
    unsigned short* hbuf  = (unsigned short*)take((size_t)N_NODES * NHID * 2);
    unsigned short* s2buf = (unsigned short*)take((size_t)N_NODES * NFEAT * 2);

    hipMemsetAsync(deg, 0, (size_t)N_NODES * 4, stream);
    hist_kernel<<<(N_EDGES + 255) / 256, 256, 0, stream>>>(dst, deg, N_EDGES);
    scan_kernel<<<1, 1024, 0, stream>>>(deg, row_ptr, cursor, N_NODES);
    fill_kernel<<<(N_EDGES + 255) / 256, 256, 0, stream>>>(src, dst, adj_vals, cursor,
                                                           csr_src, csr_val, N_EDGES);
    transpose_cvt<<<(NFEAT / 32) * (NHID / 32), 256, 0, stream>>>(W1, w1t, NFEAT, NHID);
    transpose_cvt<<<(NHID / 32) * (NFEAT / 32), 256, 0, stream>>>(W2, w2t, NHID, NFEAT);
    cvt_bf16_kernel<<<(N_NODES * NFEAT / 8 + 255) / 256, 256, 0, stream>>>(
        x, xbf, N_NODES * NFEAT / 8);

    agg1_kernel<<<N_NODES, 64, 0, stream>>>(xbf, csr_src, csr_val, row_ptr, agg1b);

    const int grid = (N_NODES + 127) / 128;  // 157
    // GEMM1: [20000,512] x [512,1024] — 4 waves, 32 rows/wave, NB=64
    gemm_rs<1, 4, 2, 4, 16><<<grid, 256, 0, stream>>>(agg1b, w1t, hbuf,
                                                      N_NODES, NHID, b1, u_drop);
    // GEMM2: [20000,1024] x [1024,512] — 8 waves, 16 rows/wave, NB=32
    gemm_rs<0, 8, 1, 2, 32><<<grid, 512, 0, stream>>>(hbuf, w2t, s2buf,
                                                      N_NODES, NFEAT, nullptr, nullptr);

    agg2_kernel<<<N_NODES, 64, 0, stream>>>(s2buf, csr_src, csr_val, row_ptr, b2, out);
}

// Round 5
// 299.722 us; speedup vs baseline: 1.4360x; 1.4360x over previous
//
#include <hip/hip_runtime.h>
#include <hip/hip_bf16.h>

typedef __attribute__((ext_vector_type(8))) short short8;
typedef __attribute__((ext_vector_type(4))) float f32x4;

#define N_NODES 20000
#define N_EDGES 320000
#define NFEAT 512
#define NHID 1024

__device__ __forceinline__ float bf2f(unsigned short u) {
    union { unsigned int i; float f; } c; c.i = ((unsigned int)u) << 16; return c.f;
}
__device__ __forceinline__ unsigned short f2bf(float f) {
    union { float f; unsigned int i; } c; c.f = f;
    unsigned int x = c.i;
    return (unsigned short)((x + 0x7fffu + ((x >> 16) & 1u)) >> 16);
}

__device__ __forceinline__ void gload_lds16(const void* g, void* l) {
    __builtin_amdgcn_global_load_lds(
        (const __attribute__((address_space(1))) void*)g,
        (__attribute__((address_space(3))) void*)l, 16, 0, 0);
}

// ---------------- CSR build ----------------

__global__ void hist_kernel(const int* __restrict__ dst, int* __restrict__ deg, int E) {
    int e = blockIdx.x * 256 + threadIdx.x;
    if (e < E) atomicAdd(&deg[dst[e]], 1);
}

__global__ __launch_bounds__(1024) void scan_kernel(const int* __restrict__ deg,
                                                    int* __restrict__ row_ptr,
                                                    int* __restrict__ cursor, int n) {
    __shared__ int sdata[1024];
    const int t = threadIdx.x;
    constexpr int CH = 20;  // 1024*20 = 20480 >= 20000
    int base = t * CH;
    int local[CH];
    int sum = 0;
#pragma unroll
    for (int i = 0; i < CH; ++i) {
        int idx = base + i;
        int v = (idx < n) ? deg[idx] : 0;
        local[i] = sum;
        sum += v;
    }
    sdata[t] = sum;
    __syncthreads();
    for (int off = 1; off < 1024; off <<= 1) {
        int v = (t >= off) ? sdata[t - off] : 0;
        __syncthreads();
        sdata[t] += v;
        __syncthreads();
    }
    int prev = (t == 0) ? 0 : sdata[t - 1];
#pragma unroll
    for (int i = 0; i < CH; ++i) {
        int idx = base + i;
        if (idx < n) {
            int p = prev + local[i];
            row_ptr[idx] = p;
            cursor[idx]  = p;
        }
    }
    if (t == 1023) row_ptr[n] = sdata[1023];
}

__global__ void fill_kernel(const int* __restrict__ src, const int* __restrict__ dst,
                            const float* __restrict__ vals, int* __restrict__ cursor,
                            int* __restrict__ csr_src, float* __restrict__ csr_val, int E) {
    int e = blockIdx.x * 256 + threadIdx.x;
    if (e < E) {
        int d = dst[e];
        int pos = atomicAdd(&cursor[d], 1);
        csr_src[pos] = src[e];
        csr_val[pos] = vals[e];
    }
}

// ------------- W transpose + bf16 convert:  Wt[n][k] = W[k][n] -------------

__global__ void transpose_cvt(const float* __restrict__ W, unsigned short* __restrict__ Wt,
                              int K, int N) {
    __shared__ float tile[32][33];
    int ntx = N >> 5;
    int k0 = (blockIdx.x / ntx) << 5;
    int n0 = (blockIdx.x % ntx) << 5;
    int tx = threadIdx.x & 31, ty = threadIdx.x >> 5;  // ty 0..7
#pragma unroll
    for (int i = 0; i < 32; i += 8)
        tile[ty + i][tx] = W[(size_t)(k0 + ty + i) * N + n0 + tx];
    __syncthreads();
#pragma unroll
    for (int i = 0; i < 32; i += 8)
        Wt[(size_t)(n0 + ty + i) * K + k0 + tx] = f2bf(tile[tx][ty + i]);
}

// ------------- f32 -> bf16 convert (x) -------------

__global__ void cvt_bf16_kernel(const float* __restrict__ x, unsigned short* __restrict__ xb,
                                int n8) {
    int i = blockIdx.x * 256 + threadIdx.x;
    if (i < n8) {
        f32x4 v0 = ((const f32x4*)x)[i * 2];
        f32x4 v1 = ((const f32x4*)x)[i * 2 + 1];
        short8 o;
#pragma unroll
        for (int j = 0; j < 4; ++j) {
            o[j]     = (short)f2bf(v0[j]);
            o[4 + j] = (short)f2bf(v1[j]);
        }
        ((short8*)xb)[i] = o;
    }
}

// ------------- dropout mask bit-pack: bit=1 iff u > 0.5 -------------
// one block packs 1024 values -> 32 uint32 words

__global__ __launch_bounds__(256) void mask_kernel(const float* __restrict__ u,
                                                   unsigned int* __restrict__ mask) {
    __shared__ unsigned char nib[256];
    size_t base = (size_t)blockIdx.x * 1024;
    int t = threadIdx.x;
    f32x4 v = ((const f32x4*)(u + base))[t];
    unsigned n = (v[0] > 0.5f ? 1u : 0u) | (v[1] > 0.5f ? 2u : 0u) |
                 (v[2] > 0.5f ? 4u : 0u) | (v[3] > 0.5f ? 8u : 0u);
    nib[t] = (unsigned char)n;
    __syncthreads();
    if (t < 32) {
        unsigned w = 0;
#pragma unroll
        for (int i = 0; i < 8; ++i) w |= (unsigned)nib[t * 8 + i] << (i * 4);
        mask[base / 32 + t] = w;
    }
}

// ------------- aggregation 1:  agg[d] = sum_e val_e * xbf[src_e]  (bf16 in, bf16 out) -------------

__global__ __launch_bounds__(64) void agg1_kernel(const unsigned short* __restrict__ xbf,
                                                  const int* __restrict__ csr_src,
                                                  const float* __restrict__ csr_val,
                                                  const int* __restrict__ row_ptr,
                                                  unsigned short* __restrict__ agg) {
    int d = blockIdx.x;
    int l = threadIdx.x;  // 0..63, 8 bf16 each -> 512
    int e0 = row_ptr[d], e1 = row_ptr[d + 1];
    f32x4 a0 = {0.f, 0.f, 0.f, 0.f}, a1 = {0.f, 0.f, 0.f, 0.f};
    int e = e0;
    for (; e + 1 < e1; e += 2) {
        int s0 = csr_src[e], s1 = csr_src[e + 1];
        float v0 = csr_val[e], v1 = csr_val[e + 1];
        short8 w0 = *(const short8*)&xbf[(size_t)s0 * NFEAT + l * 8];
        short8 w1 = *(const short8*)&xbf[(size_t)s1 * NFEAT + l * 8];
#pragma unroll
        for (int j = 0; j < 4; ++j) {
            a0[j] += v0 * bf2f((unsigned short)w0[j]);
            a1[j] += v0 * bf2f((unsigned short)w0[4 + j]);
            a0[j] += v1 * bf2f((unsigned short)w1[j]);
            a1[j] += v1 * bf2f((unsigned short)w1[4 + j]);
        }
    }
    if (e < e1) {
        int s0 = csr_src[e];
        float v0 = csr_val[e];
        short8 w0 = *(const short8*)&xbf[(size_t)s0 * NFEAT + l * 8];
#pragma unroll
        for (int j = 0; j < 4; ++j) {
            a0[j] += v0 * bf2f((unsigned short)w0[j]);
            a1[j] += v0 * bf2f((unsigned short)w0[4 + j]);
        }
    }
    short8 o;
#pragma unroll
    for (int j = 0; j < 4; ++j) {
        o[j]     = (short)f2bf(a0[j]);
        o[4 + j] = (short)f2bf(a1[j]);
    }
    *(short8*)&agg[(size_t)d * NFEAT + l * 8] = o;
}

// ------------- aggregation 2:  out[d] = b2 + sum_e val_e * s2[src_e]  (bf16 in, f32 out) -------------

__global__ __launch_bounds__(64) void agg2_kernel(const unsigned short* __restrict__ s2,
                                                  const int* __restrict__ csr_src,
                                                  const float* __restrict__ csr_val,
                                                  const int* __restrict__ row_ptr,
                                                  const float* __restrict__ b2,
                                                  float* __restrict__ out) {
    int d = blockIdx.x;
    int l = threadIdx.x;  // 0..63, 8 f32 each -> 512
    int e0 = row_ptr[d], e1 = row_ptr[d + 1];
    f32x4 a0 = ((const f32x4*)b2)[l * 2];
    f32x4 a1 = ((const f32x4*)b2)[l * 2 + 1];
    int e = e0;
    for (; e + 1 < e1; e += 2) {
        int s0 = csr_src[e], s1 = csr_src[e + 1];
        float v0 = csr_val[e], v1 = csr_val[e + 1];
        short8 w0 = *(const short8*)&s2[(size_t)s0 * NFEAT + l * 8];
        short8 w1 = *(const short8*)&s2[(size_t)s1 * NFEAT + l * 8];
#pragma unroll
        for (int j = 0; j < 4; ++j) {
            a0[j] += v0 * bf2f((unsigned short)w0[j]);
            a1[j] += v0 * bf2f((unsigned short)w0[4 + j]);
            a0[j] += v1 * bf2f((unsigned short)w1[j]);
            a1[j] += v1 * bf2f((unsigned short)w1[4 + j]);
        }
    }
    if (e < e1) {
        int s0 = csr_src[e];
        float v0 = csr_val[e];
        short8 w0 = *(const short8*)&s2[(size_t)s0 * NFEAT + l * 8];
#pragma unroll
        for (int j = 0; j < 4; ++j) {
            a0[j] += v0 * bf2f((unsigned short)w0[j]);
            a1[j] += v0 * bf2f((unsigned short)w0[4 + j]);
        }
    }
    *(f32x4*)&out[(size_t)d * NFEAT + l * 8]     = a0;
    *(f32x4*)&out[(size_t)d * NFEAT + l * 8 + 4] = a1;
}

// ------------- bf16 MFMA GEMM:  C[M,N] = A[M,K] * Bt[N,K]^T -------------
// BM=128, BN=128, BK=64, 4 waves, wave-tile 64x64, 64 KB LDS (2 blocks/CU),
// double-buffered + counted vmcnt(8) + raw barriers, XOR-swizzled (both-sides),
// bijective XCD swizzle. EPI==1: C = bf16(relu(acc+bias) * 2 * maskbit)

template <int EPI>
__global__ __launch_bounds__(256, 2) void gemm_bf16(
    const unsigned short* __restrict__ A,
    const unsigned short* __restrict__ Bt,
    unsigned short* __restrict__ C,
    int M, int N, int K,
    const float* __restrict__ bias,
    const unsigned int* __restrict__ mask) {
    __shared__ __align__(16) unsigned short lA[2][128 * 64];  // 2 x 16 KB
    __shared__ __align__(16) unsigned short lB[2][128 * 64];  // 2 x 16 KB

    // bijective XCD swizzle (m204)
    const int nwg = gridDim.x;
    const int bid = blockIdx.x;
    const int q = nwg >> 3, r = nwg & 7;
    const int xcd = bid & 7, pos = bid >> 3;
    const int swz = (xcd < r ? xcd * (q + 1) : r * (q + 1) + (xcd - r) * q) + pos;

    const int nt = N >> 7;          // tiles of 128 cols
    const int bm = swz / nt;
    const int bn = swz % nt;
    const int row0 = bm << 7;
    const int col0 = bn << 7;
    const int tid = threadIdx.x;
    const int wid = tid >> 6;       // 0..3
    const int lane = tid & 63;
    const int wr = wid >> 1, wc = wid & 1;   // wave tile 64x64
    const int rl = lane & 15;
    const int kq = lane >> 4;       // 0..3

    f32x4 acc[4][4] = {};

    // staging: one gload = 8 rows x 64 cols (64 lanes x 16B)
    const int srow = lane >> 3;                 // 0..7
    const int ksw  = (lane & 7) ^ srow;         // pre-swizzled 16B slot in global
    const int gko  = ksw * 8;                   // bf16 elems

    auto stage = [&](int buf, int k0) {
#pragma unroll
        for (int c = 0; c < 4; ++c) {           // A: 128 rows, 16 chunks, 4/wave
            int rb = wid * 8 + c * 32;
            int ga = row0 + rb + srow; if (ga >= M) ga = M - 1;
            gload_lds16(A + (size_t)ga * K + k0 + gko, &lA[buf][rb * 64]);
        }
#pragma unroll
        for (int c = 0; c < 4; ++c) {           // B: 128 rows
            int rb = wid * 8 + c * 32;
            int gb = col0 + rb + srow;
            gload_lds16(Bt + (size_t)gb * K + k0 + gko, &lB[buf][rb * 64]);
        }
    };

    const int nkt = K >> 6;
    stage(0, 0);
    asm volatile("s_waitcnt vmcnt(0)" ::: "memory");
    __builtin_amdgcn_s_barrier();
    __builtin_amdgcn_sched_barrier(0);
    int cur = 0;

    for (int kt = 0; kt < nkt; ++kt) {
        if (kt + 1 < nkt) {
            stage(cur ^ 1, (kt + 1) << 6);
            asm volatile("s_waitcnt vmcnt(8)" ::: "memory");  // cur's 8 loads done
        } else {
            asm volatile("s_waitcnt vmcnt(0)" ::: "memory");
        }
        __builtin_amdgcn_sched_barrier(0);
        __builtin_amdgcn_s_barrier();
        __builtin_amdgcn_sched_barrier(0);

#pragma unroll
        for (int ks = 0; ks < 2; ++ks) {
            const int c16 = ks * 4 + kq;        // 16B slot 0..7
            const int sw = (c16 ^ (rl & 7)) << 3;
            short8 af[4], bfr[4];
#pragma unroll
            for (int m = 0; m < 4; ++m) {
                int ra = wr * 64 + m * 16 + rl;
                af[m] = *(const short8*)&lA[cur][ra * 64 + sw];
            }
#pragma unroll
            for (int n = 0; n < 4; ++n) {
                int rb2 = wc * 64 + n * 16 + rl;
                bfr[n] = *(const short8*)&lB[cur][rb2 * 64 + sw];
            }
            __builtin_amdgcn_s_setprio(1);
#pragma unroll
            for (int m = 0; m < 4; ++m)
#pragma unroll
                for (int n = 0; n < 4; ++n)
                    acc[m][n] = __builtin_amdgcn_mfma_f32_16x16x32_bf16(af[m], bfr[n], acc[m][n], 0, 0, 0);
            __builtin_amdgcn_s_setprio(0);
        }

        __builtin_amdgcn_sched_barrier(0);
        __builtin_amdgcn_s_barrier();           // reads of buf[cur] done before overwrite
        __builtin_amdgcn_sched_barrier(0);
        cur ^= 1;
    }

    // epilogue: C/D layout col = lane&15, row = (lane>>4)*4 + j
    const int crow = kq * 4;
#pragma unroll
    for (int m = 0; m < 4; ++m) {
#pragma unroll
        for (int n = 0; n < 4; ++n) {
            int gr0 = row0 + wr * 64 + m * 16 + crow;
            int gc = col0 + wc * 64 + n * 16 + rl;
#pragma unroll
            for (int j = 0; j < 4; ++j) {
                int gr = gr0 + j;
                if (gr < M) {
                    float v = acc[m][n][j];
                    if (EPI == 1) {
                        v += bias[gc];
                        v = v > 0.f ? v : 0.f;
                        unsigned w = mask[(size_t)gr * (N >> 5) + (gc >> 5)];
                        v = ((w >> (gc & 31)) & 1u) ? v * 2.0f : 0.0f;
                    }
                    C[(size_t)gr * N + gc] = f2bf(v);
                }
            }
        }
    }
}

// ---------------- launch ----------------

extern "C" void kernel_launch(void* const* d_in, const int* in_sizes, int n_in,
                              void* d_out, int out_size, void* d_ws, size_t ws_size,
                              hipStream_t stream) {
    const float* x        = (const float*)d_in[0];
    const float* W1       = (const float*)d_in[1];
    const float* b1       = (const float*)d_in[2];
    const float* W2       = (const float*)d_in[3];
    const float* b2       = (const float*)d_in[4];
    const float* adj_vals = (const float*)d_in[5];
    const float* u_drop   = (const float*)d_in[6];
    const int*   src      = (const int*)d_in[7];
    const int*   dst      = (const int*)d_in[8];
    float* out = (float*)d_out;

    char* p = (char*)d_ws;
    auto take = [&](size_t bytes) {
        char* q = p;
        p += (bytes + 255) & ~(size_t)255;
        return q;
    };
    int* deg        = (int*)take((size_t)N_NODES * 4);
    int* row_ptr    = (int*)take((size_t)(N_NODES + 1) * 4);
    int* cursor     = (int*)take((size_t)N_NODES * 4);
    int* csr_src    = (int*)take((size_t)N_EDGES * 4);
    float* csr_val  = (float*)take((size_t)N_EDGES * 4);
    unsigned short* w1t   = (unsigned short*)take((size_t)NFEAT * NHID * 2);
    unsigned short* w2t   = (unsigned short*)take((size_t)NFEAT * NHID * 2);
    unsigned short* xbf   = (unsigned short*)take((size_t)N_NODES * NFEAT * 2);
    unsigned short* agg1b = (unsigned short*)take((size_t)N_NODES * NFEAT * 2);
    unsigned short* hbuf  = (unsigned short*)take((size_t)N_NODES * NHID * 2);
    unsigned short* s2buf = (unsigned short*)take((size_t)N_NODES * NFEAT * 2);
    unsigned int* umask   = (unsigned int*)take((size_t)N_NODES * (NHID / 32) * 4);

    hipMemsetAsync(deg, 0, (size_t)N_NODES * 4, stream);
    hist_kernel<<<(N_EDGES + 255) / 256, 256, 0, stream>>>(dst, deg, N_EDGES);
    scan_kernel<<<1, 1024, 0, stream>>>(deg, row_ptr, cursor, N_NODES);
    fill_kernel<<<(N_EDGES + 255) / 256, 256, 0, stream>>>(src, dst, adj_vals, cursor,
                                                           csr_src, csr_val, N_EDGES);
    transpose_cvt<<<(NFEAT / 32) * (NHID / 32), 256, 0, stream>>>(W1, w1t, NFEAT, NHID);
    transpose_cvt<<<(NHID / 32) * (NFEAT / 32), 256, 0, stream>>>(W2, w2t, NHID, NFEAT);
    cvt_bf16_kernel<<<(N_NODES * NFEAT / 8 + 255) / 256, 256, 0, stream>>>(
        x, xbf, N_NODES * NFEAT / 8);
    mask_kernel<<<N_NODES * NHID / 1024, 256, 0, stream>>>(u_drop, umask);

    agg1_kernel<<<N_NODES, 64, 0, stream>>>(xbf, csr_src, csr_val, row_ptr, agg1b);

    const int mt = (N_NODES + 127) / 128;  // 157
    gemm_bf16<1><<<mt * (NHID / 128), 256, 0, stream>>>(agg1b, w1t, hbuf,
                                                        N_NODES, NHID, NFEAT, b1, umask);
    gemm_bf16<0><<<mt * (NFEAT / 128), 256, 0, stream>>>(hbuf, w2t, s2buf,
                                                         N_NODES, NFEAT, NHID, nullptr, nullptr);

    agg2_kernel<<<N_NODES, 64, 0, stream>>>(s2buf, csr_src, csr_val, row_ptr, b2, out);
}